// Round 5
// baseline (634.334 us; speedup 1.0000x reference)
//
#include <hip/hip_runtime.h>
#include <hip/hip_cooperative_groups.h>
#include <stdint.h>
#include <stddef.h>

namespace cg = cooperative_groups;

// HiPPO-LegS scan as chunked causal convolution, fp16 MFMA, fp32 accumulate.
// R8: attack the measured per-step serialization in the 6 power rounds
// (R7: setup 268us, products ~200us = 33us/round, MfmaUtil 1.1% -> latency).
//  (1) LD 72+pad -> LD 64 + universal swizzle c ^= ((row^(row>>3))&7)<<3.
//      Conflict-free for row-strip writes, transpose column writes (rows
//      differing by multiples of 8 -- defeats plain (row&7) swizzles),
//      reversed-window writes, and mm64's 16-lane ds_read_b128 (the old +8
//      pad was load-bearing there). LDS: setup = As dbuf 32K + Bs 32K = 64K
//      exactly; pass2 = 48K.
//  (2) Product rounds: As double-buffered (1 barrier per A-step, was 2),
//      Bs single-buffered with register prefetch issued >=1 mm64 ahead.
//      Step order per cc: (AL*BH),(AH*BH),(AH*BL) -> 8 B-stages + 12 A-steps.
//  (3) pass2 reverted to R6 synchronous structure (R7's prefetch +
//      launch_bounds(512,4) regressed ~27us -- inferred VGPR-cap spills).
// Sync structure unchanged: 9 unconditional grid.syncs, no flags.
// Precision unchanged: dA powers split hi/lo fp16; K/x hi-only; V/C fp32.

typedef _Float16 f16;
typedef f16 half8 __attribute__((ext_vector_type(8)));
typedef float f32x4 __attribute__((ext_vector_type(4)));

#define SEQL 2048
#define NB 128
#define NS 256
#define PADROWS 64
#define LD 64    // LDS leading dim (halves); swizzle handles banks, no pad
#define LDC 280  // scan C-exchange leading dim (halves), padded layout

#define SCAN0 56   // blocks 56..63: sequential scan slices

__device__ __forceinline__ int swz(int row) { return ((row ^ (row >> 3)) & 7) << 3; }

__device__ __forceinline__ half8 h8zero() {
  half8 v;
#pragma unroll
  for (int u = 0; u < 8; u++) v[u] = (f16)0.f;
  return v;
}

// --- staging helpers (blockDim.x == 512); swizzled LDS writes ---

__device__ __forceinline__ void stage_rows(f16* dst, int nrows,
                                           const f16* src, int sstride,
                                           int nvalid, int tid) {
  int tasks = nrows * 8;
  for (int i = tid; i < tasks; i += 512) {
    int row = i >> 3, c = (i & 7) << 3;
    half8 v = h8zero();
    if (row < nvalid) v = *(const half8*)(src + (size_t)row * sstride + c);
    *(half8*)(dst + row * LD + (c ^ swz(row))) = v;
  }
}

__device__ __forceinline__ void stage_rows32(f16* dst, int nrows,
                                             const float* src, int sstride, int tid) {
  int tasks = nrows * 8;
  for (int i = tid; i < tasks; i += 512) {
    int row = i >> 3, c = (i & 7) << 3;
    const float* p = src + (size_t)row * sstride + c;
    half8 v;
#pragma unroll
    for (int u = 0; u < 8; u++) v[u] = (f16)p[u];
    *(half8*)(dst + row * LD + (c ^ swz(row))) = v;
  }
}

// As[b][q] = xpad[PADROWS + s_top - q][b]  (q=0..63, b=0..127), 0 if s < s_min
__device__ __forceinline__ void stage_revtrans(f16* As, const f16* xpad,
                                               int s_top, int s_min, int tid) {
  for (int i = tid; i < 1024; i += 512) {
    int q = i >> 4, bb = (i & 15) << 3;
    int s = s_top - q;
    half8 v = h8zero();
    if (s >= s_min) v = *(const half8*)(xpad + (size_t)(PADROWS + s) * NB + bb);
#pragma unroll
    for (int u = 0; u < 8; u++) {
      int row = bb + u;
      As[row * LD + (q ^ swz(row))] = v[u];
    }
  }
}

// --- register-prefetch stagers (T14: load early, LDS-write late) ---

template <int NT>
struct RowsPrefetch {
  half8 v[NT];
  __device__ __forceinline__ void load(const f16* src, int sstride, int nvalid, int tid) {
#pragma unroll
    for (int j = 0; j < NT; j++) {
      int i = tid + j * 512;
      int row = i >> 3, c = (i & 7) << 3;
      v[j] = (row < nvalid) ? *(const half8*)(src + (size_t)row * sstride + c)
                            : h8zero();
    }
  }
  __device__ __forceinline__ void store(f16* dst, int tid) {
#pragma unroll
    for (int j = 0; j < NT; j++) {
      int i = tid + j * 512;
      int row = i >> 3, c = (i & 7) << 3;
      *(half8*)(dst + row * LD + (c ^ swz(row))) = v[j];
    }
  }
};

// transposed B stage: Bs[j][c] = X[(c0+c)*NS + j]; NT=4 covers 64 cols x 256 j
template <int NT>
struct TransPrefetch {
  half8 v[NT];
  __device__ __forceinline__ void load(const f16* X, int c0, int tid) {
#pragma unroll
    for (int j = 0; j < NT; j++) {
      int i = tid + j * 512;
      int c = i >> 5, jj = (i & 31) << 3;
      v[j] = *(const half8*)(X + (size_t)(c0 + c) * NS + jj);
    }
  }
  __device__ __forceinline__ void store(f16* Bs, int tid) {
#pragma unroll
    for (int j = 0; j < NT; j++) {
      int i = tid + j * 512;
      int c = i >> 5, jj = (i & 31) << 3;
#pragma unroll
      for (int u = 0; u < 8; u++) {
        int row = jj + u;
        Bs[row * LD + (c ^ swz(row))] = v[j][u];
      }
    }
  }
};

// --- MFMA core: one BK=64 chunk, block tile 128x256, 8 waves as 2(m) x 4(n) ---
__device__ __forceinline__ void mm64(const f16* As, const f16* Bs,
                                     f32x4 acc[4][4], int wm, int wn,
                                     int l15, int quad) {
#pragma unroll
  for (int ks = 0; ks < 64; ks += 32) {
    half8 a[4], b[4];
#pragma unroll
    for (int ms = 0; ms < 4; ms++) {
      int ar = wm * 64 + ms * 16 + l15;
      a[ms] = *(const half8*)(As + ar * LD + ((ks + quad * 8) ^ swz(ar)));
    }
#pragma unroll
    for (int ns = 0; ns < 4; ns++) {
      int br = wn * 64 + ns * 16 + l15;
      b[ns] = *(const half8*)(Bs + br * LD + ((ks + quad * 8) ^ swz(br)));
    }
#pragma unroll
    for (int ms = 0; ms < 4; ms++)
#pragma unroll
      for (int ns = 0; ns < 4; ns++)
        acc[ms][ns] = __builtin_amdgcn_mfma_f32_16x16x32_f16(a[ms], b[ns], acc[ms][ns], 0, 0, 0);
  }
}

__device__ __forceinline__ void acc_zero(f32x4 acc[4][4]) {
#pragma unroll
  for (int ms = 0; ms < 4; ms++)
#pragma unroll
    for (int ns = 0; ns < 4; ns++)
#pragma unroll
      for (int u = 0; u < 4; u++) acc[ms][ns][u] = 0.f;
}

// C/D layout: b = wm*64+ms*16+quad*4+u, n = wn*64+ns*16+l15 (verified R2)
__device__ __forceinline__ void acc_store_split(const f32x4 acc[4][4], f16* H, f16* L,
                                                int rowoff, int wm, int wn, int l15, int quad) {
#pragma unroll
  for (int ms = 0; ms < 4; ms++)
#pragma unroll
    for (int ns = 0; ns < 4; ns++)
#pragma unroll
      for (int u = 0; u < 4; u++) {
        int row = rowoff + wm * 64 + ms * 16 + quad * 4 + u;
        int col = wn * 64 + ns * 16 + l15;
        float v = acc[ms][ns][u];
        f16 h = (f16)v;
        H[(size_t)row * NS + col] = h;
        L[(size_t)row * NS + col] = (f16)(v - (float)h);
      }
}

__device__ __forceinline__ void acc_store_f32(const f32x4 acc[4][4], float* dst,
                                              int wm, int wn, int l15, int quad) {
#pragma unroll
  for (int ms = 0; ms < 4; ms++)
#pragma unroll
    for (int ns = 0; ns < 4; ns++)
#pragma unroll
      for (int u = 0; u < 4; u++)
        dst[(size_t)(wm * 64 + ms * 16 + quad * 4 + u) * NS +
            wn * 64 + ns * 16 + l15] = acc[ms][ns][u];
}

// Pipelined 3-pass split product: D = A*B with A,B split hi/lo, drop lo*lo.
// AsD = double buffer [2][128*LD]; Bs single buffer with reg-prefetch.
// Per cc: S1 = AL*BH (1 barrier), S2 = AH*BH, B-swap to BL, S3 = AH*BL,
// B-swap to BH(cc+1). All global loads issue >=1 mm64 ahead of their use.
__device__ __forceinline__ void product_split_v2(const f16* AH, const f16* AL,
                                                 const f16* BH, const f16* BL,
                                                 f16* DH, f16* DL, int mtile,
                                                 f16* AsD, f16* Bs,
                                                 int tid, int wm, int wn,
                                                 int l15, int quad) {
  f32x4 acc[4][4];
  acc_zero(acc);
  RowsPrefetch<2> ap;
  TransPrefetch<4> bp;
  const size_t arow = (size_t)(mtile * 128) * NS;
  f16* A0 = AsD;            // buffer 0
  f16* A1 = AsD + 128 * LD; // buffer 1
  // prologue: Bs = BH(0), A[ab] = AL(0)
  bp.load(BH, 0, tid);
  ap.load(AL + arow, NS, 128, tid);
  bp.store(Bs, tid);
  ap.store(A0, tid);
  __syncthreads();
  int ab = 0;
#pragma unroll 1
  for (int cc = 0; cc < 4; cc++) {
    f16* Acur = ab ? A1 : A0;
    f16* Anxt = ab ? A0 : A1;
    // --- S1: acc += AL(cc)*BH(cc); prefetch+stage AH(cc) into other A buf ---
    ap.load(AH + arow + cc * 64, NS, 128, tid);
    mm64(Acur, Bs, acc, wm, wn, l15, quad);
    ap.store(Anxt, tid);  // Anxt's last readers finished >=2 barriers ago
    __syncthreads();
    ab ^= 1;
    Acur = ab ? A1 : A0;
    Anxt = ab ? A0 : A1;
    // --- S2: acc += AH(cc)*BH(cc); prefetch BL(cc) ---
    bp.load(BL, cc * 64, tid);
    mm64(Acur, Bs, acc, wm, wn, l15, quad);
    __syncthreads();  // all waves done reading BH(cc)
    bp.store(Bs, tid);
    if (cc < 3) ap.load(AL + arow + (cc + 1) * 64, NS, 128, tid);
    __syncthreads();  // BL(cc) visible
    // --- S3: acc += AH(cc)*BL(cc); prefetch BH(cc+1) ---
    if (cc < 3) bp.load(BH, (cc + 1) * 64, tid);
    mm64(Acur, Bs, acc, wm, wn, l15, quad);
    if (cc < 3) {
      ap.store(Anxt, tid);  // AL(cc+1); Anxt readers done since S1 barrier
      __syncthreads();      // Bs readers done + AL visible
      bp.store(Bs, tid);    // BH(cc+1)
      __syncthreads();      // visible
      ab ^= 1;
    }
  }
  acc_store_split(acc, DH, DL, mtile * 128, wm, wn, l15, quad);
}

// ===================== cooperative setup kernel (grid = 64 x 512) ==========
__global__ void __launch_bounds__(512)
k_setup(const float* __restrict__ x, const float* __restrict__ dA,
        const float* __restrict__ dB,
        f16* __restrict__ PrH, f16* __restrict__ PrL,
        f16* __restrict__ Kt, f16* __restrict__ xpad,
        float* __restrict__ V0, float* __restrict__ V1) {
  cg::grid_group grid = cg::this_grid();
  __shared__ alignas(16) f16 AsD[2 * 128 * LD];  // 32 KB: A double buffer
  __shared__ alignas(16) f16 BsS[256 * LD];      // 32 KB: B single buffer
  int tid = threadIdx.x;
  int lane = tid & 63, wid = tid >> 6;
  int wm = wid >> 2, wn = wid & 3;
  int l15 = lane & 15, quad = lane >> 4;
  int bi = blockIdx.x;

  // --- phase 0: prep (xpad fp16 [s][b]; dA split hi/lo = dA^1) ---
  {
    const int XPN = (PADROWS + SEQL) * NB;  // 270336
    for (int g = bi * 512 + tid; g < XPN; g += 64 * 512) {
      int s = g >> 7;  // /NB
      xpad[g] = (s < PADROWS) ? (f16)0.f : (f16)x[g - PADROWS * NB];
    }
    for (int g = bi * 512 + tid; g < NS * NS; g += 64 * 512) {
      float v = dA[g];
      f16 h = (f16)v;
      PrH[g] = h;
      PrL[g] = (f16)(v - (float)h);
    }
  }
  grid.sync();  // sync 1

  // --- power rounds: dA^{m+r} = dA^m dA^r (r=1..m), 2 blocks per product ---
#pragma unroll 1
  for (int m = 1; m <= 32; m <<= 1) {
    if (bi < 2 * m) {
      int prod = bi >> 1, mtile = bi & 1, r = prod + 1;  // product index m+r
      product_split_v2(PrH + (size_t)(m - 1) * 65536, PrL + (size_t)(m - 1) * 65536,
                       PrH + (size_t)(r - 1) * 65536, PrL + (size_t)(r - 1) * 65536,
                       PrH + (size_t)(m + r - 1) * 65536, PrL + (size_t)(m + r - 1) * 65536,
                       mtile, AsD, BsS, tid, wm, wn, l15, quad);
    }
    grid.sync();  // syncs 2..7
  }

  // --- K phase: K[j] = dA^j dB, j = bi -> Kt[n][j] (stride 64) ---
  {
    float* dBs = (float*)AsD;  // alias (products done; K uses no As/Bs tiles)
    if (tid < NS) dBs[tid] = dB[tid];
    __syncthreads();
    int j = bi;
    if (tid < NS) {
      int n = tid;
      float a;
      if (j == 0) {
        a = dBs[n];
      } else {
        const f16* rh = PrH + (size_t)(j - 1) * 65536 + (size_t)n * NS;
        const f16* rl = PrL + (size_t)(j - 1) * 65536 + (size_t)n * NS;
        a = 0.f;
#pragma unroll 4
        for (int c = 0; c < NS; c += 8) {
          half8 vh = *(const half8*)(rh + c);
          half8 vl = *(const half8*)(rl + c);
#pragma unroll
          for (int u = 0; u < 8; u++) a += ((float)vh[u] + (float)vl[u]) * dBs[c + u];
        }
      }
      Kt[(size_t)n * 64 + j] = (f16)a;
    }
  }
  grid.sync();  // sync 8

  // --- U phase: U_k = sum_j K[j] x[64k+63-j] -> V0[k] fp32 (blocks 0..30) ---
  if (bi < 31) {
    int k = bi, t = 64 * k + 63;
    f32x4 acc[4][4];
    acc_zero(acc);
    stage_revtrans(AsD, xpad, t, 64 * k, tid);
    stage_rows(BsS, 256, Kt, 64, 256, tid);
    __syncthreads();
    mm64(AsD, BsS, acc, wm, wn, l15, quad);
    __syncthreads();
    acc_store_f32(acc, V0 + (size_t)k * 32768, wm, wn, l15, quad);
  }
  grid.sync();  // sync 9 (final)

  // --- sequential chunk scan (blocks 56..63; 16 batch rows each) ---
  // V1[0] = U_0;  V1[k] = V1[k-1]*S^T + U_k  (states-as-rows convention).
  if (bi >= SCAN0) {
    int s = bi - SCAN0;  // slice: batch rows [16s, 16s+16)
    int w = wid;
    const f16* SH = PrH + (size_t)63 * 65536;  // S = dA^64
    const f16* SL = PrL + (size_t)63 * 65536;
    // register-resident S fragments: sf[nt][ks] = S[(2w+nt)*16+l15][ks*32+quad*8 ..+8]
    half8 sfh[2][8], sfl[2][8];
#pragma unroll
    for (int nt = 0; nt < 2; nt++) {
      int n = (w * 2 + nt) * 16 + l15;
#pragma unroll
      for (int ks2 = 0; ks2 < 8; ks2++) {
        sfh[nt][ks2] = *(const half8*)(SH + (size_t)n * NS + ks2 * 32 + quad * 8);
        sfl[nt][ks2] = *(const half8*)(SL + (size_t)n * NS + ks2 * 32 + quad * 8);
      }
    }
    f16* Chi = AsD;             // alias: 16*LDC*2 = 8960 halves <= 16384
    f16* Clo = AsD + 16 * LDC;
    f32x4 acc2[2];
#pragma unroll 1
    for (int k = 0; k < 31; k++) {
      // acc = U_k rows of this slice
#pragma unroll
      for (int nt = 0; nt < 2; nt++) {
        int col = (w * 2 + nt) * 16 + l15;
#pragma unroll
        for (int u = 0; u < 4; u++)
          acc2[nt][u] = V0[(size_t)k * 32768 + (size_t)(s * 16 + quad * 4 + u) * NS + col];
      }
      if (k > 0) {  // acc += C_{k-1} * S^T (hi*hi + lo*hi + hi*lo)
#pragma unroll
        for (int ks2 = 0; ks2 < 8; ks2++) {
          half8 ah = *(const half8*)(Chi + l15 * LDC + ks2 * 32 + quad * 8);
          half8 al = *(const half8*)(Clo + l15 * LDC + ks2 * 32 + quad * 8);
#pragma unroll
          for (int nt = 0; nt < 2; nt++) {
            acc2[nt] = __builtin_amdgcn_mfma_f32_16x16x32_f16(ah, sfh[nt][ks2], acc2[nt], 0, 0, 0);
            acc2[nt] = __builtin_amdgcn_mfma_f32_16x16x32_f16(al, sfh[nt][ks2], acc2[nt], 0, 0, 0);
            acc2[nt] = __builtin_amdgcn_mfma_f32_16x16x32_f16(ah, sfl[nt][ks2], acc2[nt], 0, 0, 0);
          }
        }
      }
      __syncthreads();  // all waves done reading C_{k-1}
#pragma unroll
      for (int nt = 0; nt < 2; nt++) {
        int col = (w * 2 + nt) * 16 + l15;
#pragma unroll
        for (int u = 0; u < 4; u++) {
          int row = quad * 4 + u;
          float v = acc2[nt][u];
          f16 h = (f16)v;
          Chi[row * LDC + col] = h;
          Clo[row * LDC + col] = (f16)(v - (float)h);
          V1[(size_t)k * 32768 + (size_t)(s * 16 + row) * NS + col] = v;
        }
      }
      __syncthreads();  // C_k visible for next step
    }
  }
}

// --- pass2: Out[64k+r] = dA^{r+1} C_k + sum_{j<=r} K[j] x[t-j] ---
// C_k = Vfin[k-1] (fp32), C_0 = 0 (skip C-part for k=0). R6 structure.
__global__ void k_pass2(const f16* __restrict__ PrH, const f16* __restrict__ Kt,
                        const f16* __restrict__ xpad, const float* __restrict__ Vfin,
                        float* __restrict__ out) {
  __shared__ alignas(16) f16 As[128 * LD];
  __shared__ alignas(16) f16 Bs[256 * LD];
  int tid = threadIdx.x;
  int lane = tid & 63, wid = tid >> 6;
  int wm = wid >> 2, wn = wid & 3;
  int l15 = lane & 15, quad = lane >> 4;
  int bi = blockIdx.x;
  int r = bi >> 5, k = bi & 31;  // 32 consecutive blocks share dA^{r+1} (L2 locality)
  int t = 64 * k + r;
  const f16* G = PrH + (size_t)r * 65536;  // dA^{r+1}
  f32x4 acc[4][4];
  acc_zero(acc);
  if (k > 0) {
    const float* C = Vfin + (size_t)(k - 1) * 32768;
#pragma unroll 1
    for (int cc = 0; cc < 4; cc++) {  // C-part, inner dim m = 256
      stage_rows32(As, 128, C + cc * 64, NS, tid);
      stage_rows(Bs, 256, G + cc * 64, NS, 256, tid);
      __syncthreads();
      mm64(As, Bs, acc, wm, wn, l15, quad);
      __syncthreads();
    }
  }
  // window part, inner dim j = 64; mask j > r  <=>  s = t - j < 64k
  stage_revtrans(As, xpad, t, 64 * k, tid);
  stage_rows(Bs, 256, Kt, 64, 256, tid);
  __syncthreads();
  mm64(As, Bs, acc, wm, wn, l15, quad);
  acc_store_f32(acc, out + (size_t)t * (NB * NS), wm, wn, l15, quad);
}

extern "C" void kernel_launch(void* const* d_in, const int* in_sizes, int n_in,
                              void* d_out, int out_size, void* d_ws, size_t ws_size,
                              hipStream_t stream) {
  const float* x = (const float*)d_in[0];   // (2048, 128)
  const float* dA = (const float*)d_in[1];  // (256, 256)
  const float* dB = (const float*)d_in[2];  // (256,)
  float* out = (float*)d_out;

  char* ws = (char*)d_ws;
  f16* PrH = (f16*)(ws + 0);            // 64 x 65536 f16 (dA^1..dA^64) hi
  f16* PrL = (f16*)(ws + 8388608);      // lo
  f16* Kt  = (f16*)(ws + 17825792);     // [n][j] 256x64 f16
  f16* Xp  = (f16*)(ws + 17858560);     // [2112][128] f16
  float* V0 = (float*)(ws + 18399232);  // 31 x 128x256 fp32 chunk sums U_k
  float* V1 = (float*)(ws + 22462464);  // scan result C_1..C_31
  // total ws use: 26,525,696 B (~25.3 MB)

  void* args[] = {&x, &dA, &dB, &PrH, &PrL, &Kt, &Xp, &V0, &V1};
  hipLaunchCooperativeKernel(reinterpret_cast<void*>(k_setup), dim3(64), dim3(512),
                             args, 0, stream);
  k_pass2<<<2048, 512, 0, stream>>>(PrH, Kt, Xp, V1, out);
}

// Round 6
// 604.032 us; speedup vs baseline: 1.0502x; 1.0502x over previous
//
#include <hip/hip_runtime.h>
#include <hip/hip_cooperative_groups.h>
#include <stdint.h>
#include <stddef.h>

namespace cg = cooperative_groups;

// HiPPO-LegS scan as chunked causal convolution, fp16 MFMA, fp32 accumulate.
// R9: recombination of best-measured halves (no new structure).
//  Measured: setup R6/R7/R8 = 312/268/315; (total-setup) = 321/348/319.
//  -> setup = R7's product_split_pipe EXACTLY (LDA/LDB=72 pad + (row&56) XOR,
//     56.3KB LDS, loads issued one mm64 ahead, 2 barriers/step);
//  -> pass2 = R8's synchronous version EXACTLY (LD=64 + full swizzle, 48KB).
//  R8's product v2 regression: single-Bs buffer put the 32-scalar-write
//  transpose scatter on the barrier critical path twice per cc. R7's pass2
//  regression: prefetch needs +16 VGPR -> either 1 block/CU (no cap) or
//  spills (cap): structural dead end at 512 threads.
// Sync structure: 9 unconditional grid.syncs, no flags (R4/R5 flag polling
// hung: relaxed agent-scope loads can poll a stale non-coherent L2 line).
// Precision: dA powers split hi/lo fp16 (R2); K/x hi-only; V/C fp32.

typedef _Float16 f16;
typedef f16 half8 __attribute__((ext_vector_type(8)));
typedef float f32x4 __attribute__((ext_vector_type(4)));

#define SEQL 2048
#define NB 128
#define NS 256
#define PADROWS 64
#define LDA 72   // setup LDS leading dim (halves): 16B-aligned rows, pad
#define LDB 72
#define LDP 64   // pass2 LDS leading dim (halves): swizzled, no pad
#define LDC 280  // scan C-exchange leading dim (halves)

#define SCAN0 56   // blocks 56..63: sequential scan slices

__device__ __forceinline__ half8 h8zero() {
  half8 v;
#pragma unroll
  for (int u = 0; u < 8; u++) v[u] = (f16)0.f;
  return v;
}

// ===================== setup helpers (LDA/LDB = 72, col ^= (row & 56)) =====

__device__ __forceinline__ void stage_rows(f16* dst, int ld, int nrows,
                                           const f16* src, int sstride,
                                           int nvalid, int tid) {
  int tasks = nrows * 8;
  for (int i = tid; i < tasks; i += 512) {
    int row = i >> 3, c = (i & 7) << 3;
    half8 v = h8zero();
    if (row < nvalid) v = *(const half8*)(src + (size_t)row * sstride + c);
    *(half8*)(dst + row * ld + (c ^ (row & 56))) = v;
  }
}

// As[b][q] = xpad[PADROWS + s_top - q][b]  (q=0..63, b=0..127), 0 if s < s_min
__device__ __forceinline__ void stage_revtrans(f16* As, const f16* xpad,
                                               int s_top, int s_min, int tid) {
  for (int i = tid; i < 1024; i += 512) {
    int q = i >> 4, bb = (i & 15) << 3;
    int s = s_top - q;
    half8 v = h8zero();
    if (s >= s_min) v = *(const half8*)(xpad + (size_t)(PADROWS + s) * NB + bb);
#pragma unroll
    for (int u = 0; u < 8; u++) {
      int row = bb + u;
      As[row * LDA + (q ^ (row & 56))] = v[u];
    }
  }
}

// register-prefetch stagers (T14: load early, LDS-write late)
template <int NT>
struct RowsPrefetch {
  half8 v[NT];
  __device__ __forceinline__ void load(const f16* src, int sstride, int nvalid, int tid) {
#pragma unroll
    for (int j = 0; j < NT; j++) {
      int i = tid + j * 512;
      int row = i >> 3, c = (i & 7) << 3;
      v[j] = (row < nvalid) ? *(const half8*)(src + (size_t)row * sstride + c)
                            : h8zero();
    }
  }
  __device__ __forceinline__ void store(f16* dst, int ld, int tid) {
#pragma unroll
    for (int j = 0; j < NT; j++) {
      int i = tid + j * 512;
      int row = i >> 3, c = (i & 7) << 3;
      *(half8*)(dst + row * ld + (c ^ (row & 56))) = v[j];
    }
  }
};

// transposed B stage: Bs[j][c] = X[(c0+c)*NS + j]; NT=4 covers 64 cols x 256 j
template <int NT>
struct TransPrefetch {
  half8 v[NT];
  __device__ __forceinline__ void load(const f16* X, int c0, int tid) {
#pragma unroll
    for (int j = 0; j < NT; j++) {
      int i = tid + j * 512;
      int c = i >> 5, jj = (i & 31) << 3;
      v[j] = *(const half8*)(X + (size_t)(c0 + c) * NS + jj);
    }
  }
  __device__ __forceinline__ void store(f16* Bs, int tid) {
#pragma unroll
    for (int j = 0; j < NT; j++) {
      int i = tid + j * 512;
      int c = i >> 5, jj = (i & 31) << 3;
#pragma unroll
      for (int u = 0; u < 8; u++) {
        int row = jj + u;
        Bs[row * LDB + (c ^ (row & 56))] = v[j][u];
      }
    }
  }
};

// MFMA core: one BK=64 chunk, block tile 128x256, 8 waves as 2(m) x 4(n)
__device__ __forceinline__ void mm64(const f16* As, const f16* Bs,
                                     f32x4 acc[4][4], int wm, int wn,
                                     int l15, int quad) {
#pragma unroll
  for (int ks = 0; ks < 64; ks += 32) {
    half8 a[4], b[4];
#pragma unroll
    for (int ms = 0; ms < 4; ms++) {
      int ar = wm * 64 + ms * 16 + l15;
      a[ms] = *(const half8*)(As + ar * LDA + ((ks + quad * 8) ^ (ar & 56)));
    }
#pragma unroll
    for (int ns = 0; ns < 4; ns++) {
      int br = wn * 64 + ns * 16 + l15;
      b[ns] = *(const half8*)(Bs + br * LDB + ((ks + quad * 8) ^ (br & 56)));
    }
#pragma unroll
    for (int ms = 0; ms < 4; ms++)
#pragma unroll
      for (int ns = 0; ns < 4; ns++)
        acc[ms][ns] = __builtin_amdgcn_mfma_f32_16x16x32_f16(a[ms], b[ns], acc[ms][ns], 0, 0, 0);
  }
}

// ===================== pass2 helpers (LDP = 64, swizzled) ==================

__device__ __forceinline__ int swz(int row) { return ((row ^ (row >> 3)) & 7) << 3; }

__device__ __forceinline__ void stage_rows_s(f16* dst, int nrows,
                                             const f16* src, int sstride,
                                             int nvalid, int tid) {
  int tasks = nrows * 8;
  for (int i = tid; i < tasks; i += 512) {
    int row = i >> 3, c = (i & 7) << 3;
    half8 v = h8zero();
    if (row < nvalid) v = *(const half8*)(src + (size_t)row * sstride + c);
    *(half8*)(dst + row * LDP + (c ^ swz(row))) = v;
  }
}

__device__ __forceinline__ void stage_rows32_s(f16* dst, int nrows,
                                               const float* src, int sstride, int tid) {
  int tasks = nrows * 8;
  for (int i = tid; i < tasks; i += 512) {
    int row = i >> 3, c = (i & 7) << 3;
    const float* p = src + (size_t)row * sstride + c;
    half8 v;
#pragma unroll
    for (int u = 0; u < 8; u++) v[u] = (f16)p[u];
    *(half8*)(dst + row * LDP + (c ^ swz(row))) = v;
  }
}

__device__ __forceinline__ void stage_revtrans_s(f16* As, const f16* xpad,
                                                 int s_top, int s_min, int tid) {
  for (int i = tid; i < 1024; i += 512) {
    int q = i >> 4, bb = (i & 15) << 3;
    int s = s_top - q;
    half8 v = h8zero();
    if (s >= s_min) v = *(const half8*)(xpad + (size_t)(PADROWS + s) * NB + bb);
#pragma unroll
    for (int u = 0; u < 8; u++) {
      int row = bb + u;
      As[row * LDP + (q ^ swz(row))] = v[u];
    }
  }
}

__device__ __forceinline__ void mm64_s(const f16* As, const f16* Bs,
                                       f32x4 acc[4][4], int wm, int wn,
                                       int l15, int quad) {
#pragma unroll
  for (int ks = 0; ks < 64; ks += 32) {
    half8 a[4], b[4];
#pragma unroll
    for (int ms = 0; ms < 4; ms++) {
      int ar = wm * 64 + ms * 16 + l15;
      a[ms] = *(const half8*)(As + ar * LDP + ((ks + quad * 8) ^ swz(ar)));
    }
#pragma unroll
    for (int ns = 0; ns < 4; ns++) {
      int br = wn * 64 + ns * 16 + l15;
      b[ns] = *(const half8*)(Bs + br * LDP + ((ks + quad * 8) ^ swz(br)));
    }
#pragma unroll
    for (int ms = 0; ms < 4; ms++)
#pragma unroll
      for (int ns = 0; ns < 4; ns++)
        acc[ms][ns] = __builtin_amdgcn_mfma_f32_16x16x32_f16(a[ms], b[ns], acc[ms][ns], 0, 0, 0);
  }
}

// ===================== shared accumulator helpers ==========================

__device__ __forceinline__ void acc_zero(f32x4 acc[4][4]) {
#pragma unroll
  for (int ms = 0; ms < 4; ms++)
#pragma unroll
    for (int ns = 0; ns < 4; ns++)
#pragma unroll
      for (int u = 0; u < 4; u++) acc[ms][ns][u] = 0.f;
}

// C/D layout: b = wm*64+ms*16+quad*4+u, n = wn*64+ns*16+l15 (verified R2)
__device__ __forceinline__ void acc_store_split(const f32x4 acc[4][4], f16* H, f16* L,
                                                int rowoff, int wm, int wn, int l15, int quad) {
#pragma unroll
  for (int ms = 0; ms < 4; ms++)
#pragma unroll
    for (int ns = 0; ns < 4; ns++)
#pragma unroll
      for (int u = 0; u < 4; u++) {
        int row = rowoff + wm * 64 + ms * 16 + quad * 4 + u;
        int col = wn * 64 + ns * 16 + l15;
        float v = acc[ms][ns][u];
        f16 h = (f16)v;
        H[(size_t)row * NS + col] = h;
        L[(size_t)row * NS + col] = (f16)(v - (float)h);
      }
}

__device__ __forceinline__ void acc_store_f32(const f32x4 acc[4][4], float* dst,
                                              int wm, int wn, int l15, int quad) {
#pragma unroll
  for (int ms = 0; ms < 4; ms++)
#pragma unroll
    for (int ns = 0; ns < 4; ns++)
#pragma unroll
      for (int u = 0; u < 4; u++)
        dst[(size_t)(wm * 64 + ms * 16 + quad * 4 + u) * NS +
            wn * 64 + ns * 16 + l15] = acc[ms][ns][u];
}

// Pipelined 3-pass split product (R7, measured 268us setup): D = A*B hi/lo,
// drop lo*lo. 12 steps cc-major; per cc (AL*BH),(AH*BH),(AH*BL) reuses the
// staged operand between adjacent steps (8 As + 8 Bs restages). Per step:
// issue next-step global loads -> mm64 -> bar -> LDS write next -> bar.
__device__ __forceinline__ void product_split_pipe(const f16* AH, const f16* AL,
                                                   const f16* BH, const f16* BL,
                                                   f16* DH, f16* DL, int mtile,
                                                   f16* As, f16* Bs,
                                                   int tid, int wm, int wn,
                                                   int l15, int quad) {
  f32x4 acc[4][4];
  acc_zero(acc);
  RowsPrefetch<2> ap;   // 128 rows x 64 cols
  TransPrefetch<4> bp;  // 256 rows x 64 cols transposed
  const size_t arow = (size_t)(mtile * 128) * NS;
  // prologue: step 0 = (AL * BH), cc = 0
  ap.load(AL + arow, NS, 128, tid);
  bp.load(BH, 0, tid);
  ap.store(As, LDA, tid);
  bp.store(Bs, tid);
  __syncthreads();
#pragma unroll 1
  for (int s = 0; s < 12; s++) {
    int sn = s + 1;
    int restA = 0, restB = 0;
    if (sn < 12) {
      int c3 = sn % 3, ccn = sn / 3;
      if (c3 == 0) {        // next = (AL * BH) of cc+1
        ap.load(AL + arow + ccn * 64, NS, 128, tid);
        bp.load(BH, ccn * 64, tid);
        restA = restB = 1;
      } else if (c3 == 1) { // next = (AH * BH): A changes
        ap.load(AH + arow + ccn * 64, NS, 128, tid);
        restA = 1;
      } else {              // next = (AH * BL): B changes
        bp.load(BL, ccn * 64, tid);
        restB = 1;
      }
    }
    mm64(As, Bs, acc, wm, wn, l15, quad);
    __syncthreads();  // everyone done reading As/Bs
    if (restA) ap.store(As, LDA, tid);
    if (restB) bp.store(Bs, tid);
    __syncthreads();  // next tile visible
  }
  acc_store_split(acc, DH, DL, mtile * 128, wm, wn, l15, quad);
}

// ===================== cooperative setup kernel (grid = 64 x 512) ==========
__global__ void __launch_bounds__(512)
k_setup(const float* __restrict__ x, const float* __restrict__ dA,
        const float* __restrict__ dB,
        f16* __restrict__ PrH, f16* __restrict__ PrL,
        f16* __restrict__ Kt, f16* __restrict__ xpad,
        float* __restrict__ V0, float* __restrict__ V1) {
  cg::grid_group grid = cg::this_grid();
  __shared__ alignas(16) f16 As[128 * LDA];
  __shared__ alignas(16) f16 Bs[256 * LDB];
  __shared__ float dBs[NS];
  int tid = threadIdx.x;
  int lane = tid & 63, wid = tid >> 6;
  int wm = wid >> 2, wn = wid & 3;
  int l15 = lane & 15, quad = lane >> 4;
  int bi = blockIdx.x;

  // --- phase 0: prep (xpad fp16 [s][b]; dA split hi/lo = dA^1) ---
  {
    const int XPN = (PADROWS + SEQL) * NB;  // 270336
    for (int g = bi * 512 + tid; g < XPN; g += 64 * 512) {
      int s = g >> 7;  // /NB
      xpad[g] = (s < PADROWS) ? (f16)0.f : (f16)x[g - PADROWS * NB];
    }
    for (int g = bi * 512 + tid; g < NS * NS; g += 64 * 512) {
      float v = dA[g];
      f16 h = (f16)v;
      PrH[g] = h;
      PrL[g] = (f16)(v - (float)h);
    }
  }
  grid.sync();  // sync 1

  // --- power rounds: dA^{m+r} = dA^m dA^r (r=1..m), 2 blocks per product ---
#pragma unroll 1
  for (int m = 1; m <= 32; m <<= 1) {
    if (bi < 2 * m) {
      int prod = bi >> 1, mtile = bi & 1, r = prod + 1;  // product index m+r
      product_split_pipe(PrH + (size_t)(m - 1) * 65536, PrL + (size_t)(m - 1) * 65536,
                         PrH + (size_t)(r - 1) * 65536, PrL + (size_t)(r - 1) * 65536,
                         PrH + (size_t)(m + r - 1) * 65536, PrL + (size_t)(m + r - 1) * 65536,
                         mtile, As, Bs, tid, wm, wn, l15, quad);
    }
    grid.sync();  // syncs 2..7
  }

  // --- K phase: K[j] = dA^j dB, j = bi -> Kt[n][j] (stride 64) ---
  {
    if (tid < NS) dBs[tid] = dB[tid];
    __syncthreads();
    int j = bi;
    if (tid < NS) {
      int n = tid;
      float a;
      if (j == 0) {
        a = dBs[n];
      } else {
        const f16* rh = PrH + (size_t)(j - 1) * 65536 + (size_t)n * NS;
        const f16* rl = PrL + (size_t)(j - 1) * 65536 + (size_t)n * NS;
        a = 0.f;
#pragma unroll 4
        for (int c = 0; c < NS; c += 8) {
          half8 vh = *(const half8*)(rh + c);
          half8 vl = *(const half8*)(rl + c);
#pragma unroll
          for (int u = 0; u < 8; u++) a += ((float)vh[u] + (float)vl[u]) * dBs[c + u];
        }
      }
      Kt[(size_t)n * 64 + j] = (f16)a;
    }
  }
  grid.sync();  // sync 8

  // --- U phase: U_k = sum_j K[j] x[64k+63-j] -> V0[k] fp32 (blocks 0..30) ---
  if (bi < 31) {
    int k = bi, t = 64 * k + 63;
    f32x4 acc[4][4];
    acc_zero(acc);
    stage_revtrans(As, xpad, t, 64 * k, tid);
    stage_rows(Bs, LDB, 256, Kt, 64, 256, tid);
    __syncthreads();
    mm64(As, Bs, acc, wm, wn, l15, quad);
    __syncthreads();
    acc_store_f32(acc, V0 + (size_t)k * 32768, wm, wn, l15, quad);
  }
  grid.sync();  // sync 9 (final)

  // --- sequential chunk scan (blocks 56..63; 16 batch rows each) ---
  // V1[0] = U_0;  V1[k] = V1[k-1]*S^T + U_k  (states-as-rows convention).
  if (bi >= SCAN0) {
    int s = bi - SCAN0;  // slice: batch rows [16s, 16s+16)
    int w = wid;
    const f16* SH = PrH + (size_t)63 * 65536;  // S = dA^64
    const f16* SL = PrL + (size_t)63 * 65536;
    // register-resident S fragments: sf[nt][ks] = S[(2w+nt)*16+l15][ks*32+quad*8 ..+8]
    half8 sfh[2][8], sfl[2][8];
#pragma unroll
    for (int nt = 0; nt < 2; nt++) {
      int n = (w * 2 + nt) * 16 + l15;
#pragma unroll
      for (int ks2 = 0; ks2 < 8; ks2++) {
        sfh[nt][ks2] = *(const half8*)(SH + (size_t)n * NS + ks2 * 32 + quad * 8);
        sfl[nt][ks2] = *(const half8*)(SL + (size_t)n * NS + ks2 * 32 + quad * 8);
      }
    }
    f16* Chi = As;             // alias As region: 16*LDC*2 = 8960 halves <= 9216
    f16* Clo = As + 16 * LDC;
    f32x4 acc2[2];
#pragma unroll 1
    for (int k = 0; k < 31; k++) {
      // acc = U_k rows of this slice
#pragma unroll
      for (int nt = 0; nt < 2; nt++) {
        int col = (w * 2 + nt) * 16 + l15;
#pragma unroll
        for (int u = 0; u < 4; u++)
          acc2[nt][u] = V0[(size_t)k * 32768 + (size_t)(s * 16 + quad * 4 + u) * NS + col];
      }
      if (k > 0) {  // acc += C_{k-1} * S^T (hi*hi + lo*hi + hi*lo)
#pragma unroll
        for (int ks2 = 0; ks2 < 8; ks2++) {
          half8 ah = *(const half8*)(Chi + l15 * LDC + ks2 * 32 + quad * 8);
          half8 al = *(const half8*)(Clo + l15 * LDC + ks2 * 32 + quad * 8);
#pragma unroll
          for (int nt = 0; nt < 2; nt++) {
            acc2[nt] = __builtin_amdgcn_mfma_f32_16x16x32_f16(ah, sfh[nt][ks2], acc2[nt], 0, 0, 0);
            acc2[nt] = __builtin_amdgcn_mfma_f32_16x16x32_f16(al, sfh[nt][ks2], acc2[nt], 0, 0, 0);
            acc2[nt] = __builtin_amdgcn_mfma_f32_16x16x32_f16(ah, sfl[nt][ks2], acc2[nt], 0, 0, 0);
          }
        }
      }
      __syncthreads();  // all waves done reading C_{k-1}
#pragma unroll
      for (int nt = 0; nt < 2; nt++) {
        int col = (w * 2 + nt) * 16 + l15;
#pragma unroll
        for (int u = 0; u < 4; u++) {
          int row = quad * 4 + u;
          float v = acc2[nt][u];
          f16 h = (f16)v;
          Chi[row * LDC + col] = h;
          Clo[row * LDC + col] = (f16)(v - (float)h);
          V1[(size_t)k * 32768 + (size_t)(s * 16 + row) * NS + col] = v;
        }
      }
      __syncthreads();  // C_k visible for next step
    }
  }
}

// --- pass2 (R8 structure, measured ~319 incl. gap): synchronous stages,
// LDP=64 swizzled, 48KB LDS ---
// Out[64k+r] = dA^{r+1} C_k + sum_{j<=r} K[j] x[t-j]; C_k = Vfin[k-1], C_0=0.
__global__ void k_pass2(const f16* __restrict__ PrH, const f16* __restrict__ Kt,
                        const f16* __restrict__ xpad, const float* __restrict__ Vfin,
                        float* __restrict__ out) {
  __shared__ alignas(16) f16 As[128 * LDP];
  __shared__ alignas(16) f16 Bs[256 * LDP];
  int tid = threadIdx.x;
  int lane = tid & 63, wid = tid >> 6;
  int wm = wid >> 2, wn = wid & 3;
  int l15 = lane & 15, quad = lane >> 4;
  int bi = blockIdx.x;
  int r = bi >> 5, k = bi & 31;  // 32 consecutive blocks share dA^{r+1} (L2 locality)
  int t = 64 * k + r;
  const f16* G = PrH + (size_t)r * 65536;  // dA^{r+1}
  f32x4 acc[4][4];
  acc_zero(acc);
  if (k > 0) {
    const float* C = Vfin + (size_t)(k - 1) * 32768;
#pragma unroll 1
    for (int cc = 0; cc < 4; cc++) {  // C-part, inner dim m = 256
      stage_rows32_s(As, 128, C + cc * 64, NS, tid);
      stage_rows_s(Bs, 256, G + cc * 64, NS, 256, tid);
      __syncthreads();
      mm64_s(As, Bs, acc, wm, wn, l15, quad);
      __syncthreads();
    }
  }
  // window part, inner dim j = 64; mask j > r  <=>  s = t - j < 64k
  stage_revtrans_s(As, xpad, t, 64 * k, tid);
  stage_rows_s(Bs, 256, Kt, 64, 256, tid);
  __syncthreads();
  mm64_s(As, Bs, acc, wm, wn, l15, quad);
  acc_store_f32(acc, out + (size_t)t * (NB * NS), wm, wn, l15, quad);
}

extern "C" void kernel_launch(void* const* d_in, const int* in_sizes, int n_in,
                              void* d_out, int out_size, void* d_ws, size_t ws_size,
                              hipStream_t stream) {
  const float* x = (const float*)d_in[0];   // (2048, 128)
  const float* dA = (const float*)d_in[1];  // (256, 256)
  const float* dB = (const float*)d_in[2];  // (256,)
  float* out = (float*)d_out;

  char* ws = (char*)d_ws;
  f16* PrH = (f16*)(ws + 0);            // 64 x 65536 f16 (dA^1..dA^64) hi
  f16* PrL = (f16*)(ws + 8388608);      // lo
  f16* Kt  = (f16*)(ws + 17825792);     // [n][j] 256x64 f16
  f16* Xp  = (f16*)(ws + 17858560);     // [2112][128] f16
  float* V0 = (float*)(ws + 18399232);  // 31 x 128x256 fp32 chunk sums U_k
  float* V1 = (float*)(ws + 22462464);  // scan result C_1..C_31
  // total ws use: 26,525,696 B (~25.3 MB)

  void* args[] = {&x, &dA, &dB, &PrH, &PrL, &Kt, &Xp, &V0, &V1};
  hipLaunchCooperativeKernel(reinterpret_cast<void*>(k_setup), dim3(64), dim3(512),
                             args, 0, stream);
  k_pass2<<<2048, 512, 0, stream>>>(PrH, Kt, Xp, V1, out);
}